// Round 22
// baseline (356.231 us; speedup 1.0000x reference)
//
#include <hip/hip_runtime.h>

#define N_NODES 50000
#define N_EDGES 800000
#define TOT_E   (N_EDGES + N_NODES)
#define EPS     1e-5f
#define SCAN_NB 196                      // ceil(N_NODES/256)

typedef unsigned short u16;
typedef short v8s __attribute__((ext_vector_type(8)));
typedef float v4f __attribute__((ext_vector_type(4)));

// workspace byte offsets
#define WS_W1H    0          // [64 n][32 k] bf16 hi plane   4096 B
#define WS_W1L    4096       // lo plane                     4096 B
#define WS_W2H    8192       // [64 n][64 k]                 8192 B
#define WS_W2L    16384
#define WS_W3H    24576      // [128 n][64 k]               16384 B
#define WS_W3L    40960
#define WS_B1F    57344      // 64 f32
#define WS_B2F    57600
#define WS_B3F    57856      // 128 f32
#define WS_BSUM   58368      // SCAN_NB ints (padded to 1024)
#define WS_CURSOR 59392      // N_NODES ints -> ends at 259392
#define WS_SORT   259392     // TOT_E int2 (8B aligned), 6.8 MB

__device__ __forceinline__ unsigned rne_bf16(float f) {
    unsigned u = __float_as_uint(f);
    return (u + 0x7fffu + ((u >> 16) & 1u)) >> 16;
}

// pairwise fp32 -> (bf16-hi, bf16-lo residual) via v_cvt_pk_bf16_f32 inline asm
// (guide T12/m240: no builtin on gfx950). dst = bf16(s1)<<16 | bf16(s0).
__device__ __forceinline__ void cvt_split2(float v0, float v1,
                                           unsigned &hp, unsigned &lp) {
    unsigned h;
    asm("v_cvt_pk_bf16_f32 %0, %1, %2" : "=v"(h) : "v"(v0), "v"(v1));
    float h0f = __uint_as_float(h << 16);
    float h1f = __uint_as_float(h & 0xffff0000u);
    unsigned l;
    float r0 = v0 - h0f, r1 = v1 - h1f;
    asm("v_cvt_pk_bf16_f32 %0, %1, %2" : "=v"(l) : "v"(r0), "v"(r1));
    hp = h; lp = l;
}

#define MFMA3(acc, ah, al, bh, bl)                                           \
    acc = __builtin_amdgcn_mfma_f32_16x16x32_bf16(ah, bh, acc, 0, 0, 0);     \
    acc = __builtin_amdgcn_mfma_f32_16x16x32_bf16(ah, bl, acc, 0, 0, 0);     \
    acc = __builtin_amdgcn_mfma_f32_16x16x32_bf16(al, bh, acc, 0, 0, 0);

// fused: weight fold + out=-inf + edge histogram (cursor pre-zeroed by memset)
__global__ void prep0_kernel(
    const float* __restrict__ W1, const float* __restrict__ b1,
    const float* __restrict__ g1, const float* __restrict__ be1,
    const float* __restrict__ m1, const float* __restrict__ v1,
    const float* __restrict__ W2, const float* __restrict__ b2,
    const float* __restrict__ g2, const float* __restrict__ be2,
    const float* __restrict__ m2, const float* __restrict__ v2,
    const float* __restrict__ W3, const float* __restrict__ b3,
    const float* __restrict__ g3, const float* __restrict__ be3,
    const float* __restrict__ m3, const float* __restrict__ v3,
    const int* __restrict__ ei,
    u16* __restrict__ w1h, u16* __restrict__ w1l,
    u16* __restrict__ w2h, u16* __restrict__ w2l,
    u16* __restrict__ w3h, u16* __restrict__ w3l,
    float* __restrict__ b1f, float* __restrict__ b2f, float* __restrict__ b3f,
    int* __restrict__ cursor, uint4* __restrict__ out4)
{
    int t = blockIdx.x * blockDim.x + threadIdx.x;

    if (t < (N_NODES * 128) / 4)
        out4[t] = make_uint4(0xFF800000u, 0xFF800000u, 0xFF800000u, 0xFF800000u);

    if (t < N_EDGES) atomicAdd(&cursor[ei[N_EDGES + t]], 1);   // hist (fused)

    if (t < 14592) {
        float val = 0.f;
        u16 *ph = nullptr, *pl = nullptr;
        int idx = 0;
        if (t < 2048) {                       // W1 [n][32k], k>=6 zero
            int n = t >> 5, k = t & 31;
            float s = g1[n] * rsqrtf(v1[n] + EPS);
            val = (k < 6) ? W1[k * 64 + n] * s : 0.f;
            ph = w1h; pl = w1l; idx = t;
        } else if (t < 6144) {                // W2 [n][64k]
            int i = t - 2048; int n = i >> 6, k = i & 63;
            float s = g2[n] * rsqrtf(v2[n] + EPS);
            val = W2[k * 64 + n] * s;
            ph = w2h; pl = w2l; idx = i;
        } else if (t < 14336) {               // W3 [n][64k]
            int i = t - 6144; int n = i >> 6, k = i & 63;
            float s = g3[n] * rsqrtf(v3[n] + EPS);
            val = W3[k * 128 + n] * s;
            ph = w3h; pl = w3l; idx = i;
        } else {                              // biases
            int i = t - 14336;
            if (i < 64) {
                float s = g1[i] * rsqrtf(v1[i] + EPS);
                b1f[i] = (b1[i] - m1[i]) * s + be1[i];
            } else if (i < 128) {
                int j = i - 64;
                float s = g2[j] * rsqrtf(v2[j] + EPS);
                b2f[j] = (b2[j] - m2[j]) * s + be2[j];
            } else {
                int j = i - 128;
                float s = g3[j] * rsqrtf(v3[j] + EPS);
                b3f[j] = (b3[j] - m3[j]) * s + be3[j];
            }
            return;
        }
        unsigned hi = rne_bf16(val);
        unsigned lo = rne_bf16(val - __uint_as_float(hi << 16));
        ph[idx] = (u16)hi;
        pl[idx] = (u16)lo;
    }
}

// A) per-block exclusive scan + block sums; +1 per node folds the self-loop
__global__ void scanA_kernel(int* __restrict__ cursor, int* __restrict__ bsum) {
    __shared__ int sh[256];
    const int tid = threadIdx.x;
    int i = blockIdx.x * 256 + tid;
    int c = (i < N_NODES) ? (cursor[i] + 1) : 0;     // +1 = self loop
    sh[tid] = c;
    __syncthreads();
    int v = c;
    for (int off = 1; off < 256; off <<= 1) {
        int t = (tid >= off) ? sh[tid - off] : 0;
        __syncthreads();
        v += t;
        sh[tid] = v;
        __syncthreads();
    }
    if (i < N_NODES) cursor[i] = v - c;           // exclusive within block
    if (tid == 255) bsum[blockIdx.x] = v;         // block total
}

// B) exclusive scan of the block sums
__global__ void scanB_kernel(int* __restrict__ bsum) {
    __shared__ int sh[256];
    const int tid = threadIdx.x;
    int c = (tid < SCAN_NB) ? bsum[tid] : 0;
    sh[tid] = c;
    __syncthreads();
    int v = c;
    for (int off = 1; off < 256; off <<= 1) {
        int t = (tid >= off) ? sh[tid - off] : 0;
        __syncthreads();
        v += t;
        sh[tid] = v;
        __syncthreads();
    }
    if (tid < SCAN_NB) bsum[tid] = v - c;
}

// scatter: dst-sorted (src,dst) pairs written directly
__global__ void scatter_kernel(const int* __restrict__ ei, int* __restrict__ cursor,
                               const int* __restrict__ bsum, int2* __restrict__ sorted) {
    int e = blockIdx.x * 256 + threadIdx.x;
    if (e >= TOT_E) return;
    int s, d;
    if (e < N_EDGES) { s = ei[e]; d = ei[N_EDGES + e]; }
    else             { s = d = e - N_EDGES; }
    int p = atomicAdd(&cursor[d], 1);
    sorted[p + bsum[d >> 8]] = make_int2(s, d);
}

// r18 gather + (a) 2 edge-groups per wave (warm-L1 weight reuse, half the
// blocks), (b) s_setprio(1) around MFMA clusters (T5: helps independent
// non-barrier waves; our regime == attn's +7%, not GEMM's lockstep null).
__global__ __launch_bounds__(64, 2) void gather_kernel(
    const float* __restrict__ x, const float* __restrict__ pos,
    const int2* __restrict__ sorted,
    const u16* __restrict__ w1h, const u16* __restrict__ w1l,
    const u16* __restrict__ w2h, const u16* __restrict__ w2l,
    const u16* __restrict__ w3h, const u16* __restrict__ w3l,
    const float* __restrict__ b1f, const float* __restrict__ b2f,
    const float* __restrict__ b3f, float* __restrict__ out)
{
    __shared__ char smem[12288];

    const int lane = threadIdx.x;
    const int l15 = lane & 15, g = lane >> 4;

#pragma unroll 1
    for (int grp = 0; grp < 2; ++grp) {
        const int e = blockIdx.x * 128 + grp * 64 + lane;
        const bool active = e < TOT_E;

        int src = 0, dst = 0;
        if (active) {
            int2 sd = sorted[e];
            src = sd.x; dst = sd.y;
        }
        const int nid = active ? dst : (-1 - lane);   // unique negatives in tail

        // full-exec-mask shuffles only (round-4 lesson)
        const int np1 = __shfl_down(nid, 1);
        const bool seg_last = (lane == 63) || (np1 != nid);
        const unsigned long long segmask = __ballot(seg_last);  // bit63 always set

        float f0 = x[src * 3 + 0];
        float f1 = x[src * 3 + 1];
        float f2v = x[src * 3 + 2];
        float f3 = pos[src * 3 + 0] - pos[dst * 3 + 0];
        float f4 = pos[src * 3 + 1] - pos[dst * 3 + 1];
        float f5 = pos[src * 3 + 2] - pos[dst * 3 + 2];

        unsigned uh0, ul0, uh1, ul1, uh2, ul2;
        cvt_split2(f0, f1, uh0, ul0);
        cvt_split2(f2v, f3, uh1, ul1);
        cvt_split2(f4, f5, uh2, ul2);

        // L1 A-frags via bpermute (edge 16tm+l15's features; g>0 lanes: k>=8 -> 0)
        v8s a1h[4], a1l[4];
#pragma unroll
        for (int tm = 0; tm < 4; ++tm) {
            int bidx = (16 * tm + l15) * 4;
            unsigned p0 = (unsigned)__builtin_amdgcn_ds_bpermute(bidx, (int)uh0);
            unsigned p1 = (unsigned)__builtin_amdgcn_ds_bpermute(bidx, (int)uh1);
            unsigned p2 = (unsigned)__builtin_amdgcn_ds_bpermute(bidx, (int)uh2);
            unsigned q0 = (unsigned)__builtin_amdgcn_ds_bpermute(bidx, (int)ul0);
            unsigned q1 = (unsigned)__builtin_amdgcn_ds_bpermute(bidx, (int)ul1);
            unsigned q2 = (unsigned)__builtin_amdgcn_ds_bpermute(bidx, (int)ul2);
            if (g != 0) { p0 = p1 = p2 = q0 = q1 = q2 = 0u; }
            uint4 th = make_uint4(p0, p1, p2, 0u);
            uint4 tl = make_uint4(q0, q1, q2, 0u);
            a1h[tm] = __builtin_bit_cast(v8s, th);
            a1l[tm] = __builtin_bit_cast(v8s, tl);
        }

        // ---- layer 1
        v4f acc[4][4];
#pragma unroll
        for (int tn = 0; tn < 4; ++tn) {
            float bv = b1f[16 * tn + l15];
#pragma unroll
            for (int tm = 0; tm < 4; ++tm) acc[tm][tn] = (v4f){bv, bv, bv, bv};
        }
        __builtin_amdgcn_s_setprio(1);
#pragma unroll
        for (int tn = 0; tn < 4; ++tn) {
            v8s bh = *(const v8s*)&w1h[(16 * tn + l15) * 32 + g * 8];
            v8s bl = *(const v8s*)&w1l[(16 * tn + l15) * 32 + g * 8];
#pragma unroll
            for (int tm = 0; tm < 4; ++tm) { MFMA3(acc[tm][tn], a1h[tm], a1l[tm], bh, bl) }
        }
        __builtin_amdgcn_s_setprio(0);

        // H1 transient staging into [0,8192): [row][32hi|32lo] u16, 128B rows
#define STAGE_HALF(ACC, tk)                                                      \
    {                                                                            \
        _Pragma("unroll")                                                        \
        for (int t2 = 0; t2 < 2; ++t2) {                                         \
            int tn = 2 * (tk) + t2;                                              \
            int fc = 16 * t2 + l15;                                              \
            _Pragma("unroll")                                                    \
            for (int tm = 0; tm < 4; ++tm) {                                     \
                unsigned hp0, lp0, hp1, lp1;                                     \
                cvt_split2(fmaxf(ACC[tm][tn][0], 0.f),                           \
                           fmaxf(ACC[tm][tn][1], 0.f), hp0, lp0);                \
                cvt_split2(fmaxf(ACC[tm][tn][2], 0.f),                           \
                           fmaxf(ACC[tm][tn][3], 0.f), hp1, lp1);                \
                _Pragma("unroll")                                                \
                for (int r = 0; r < 4; ++r) {                                    \
                    int row = 16 * tm + 4 * g + r;                               \
                    unsigned hv = (r == 0) ? hp0 : (r == 1) ? (hp0 >> 16)        \
                                : (r == 2) ? hp1 : (hp1 >> 16);                  \
                    unsigned lv = (r == 0) ? lp0 : (r == 1) ? (lp0 >> 16)        \
                                : (r == 2) ? lp1 : (lp1 >> 16);                  \
                    int swz = (row & 7) << 4;                                    \
                    *(u16*)(smem + row * 128 + ((fc * 2) ^ swz)) = (u16)hv;      \
                    *(u16*)(smem + row * 128 + ((64 + fc * 2) ^ swz)) = (u16)lv; \
                }                                                                \
            }                                                                    \
        }                                                                        \
    }

        // ---- layer 2: two k-half passes
        v4f acc2[4][4];
#pragma unroll
        for (int tn = 0; tn < 4; ++tn) {
            float bv = b2f[16 * tn + l15];
#pragma unroll
            for (int tm = 0; tm < 4; ++tm) acc2[tm][tn] = (v4f){bv, bv, bv, bv};
        }
#pragma unroll
        for (int tk = 0; tk < 2; ++tk) {
            STAGE_HALF(acc, tk)
            v8s ah[4], al[4];
#pragma unroll
            for (int tm = 0; tm < 4; ++tm) {
                int row = 16 * tm + l15;
                int swz = (row & 7) << 4;
                ah[tm] = *(const v8s*)(smem + row * 128 + ((g * 16) ^ swz));
                al[tm] = *(const v8s*)(smem + row * 128 + ((64 + g * 16) ^ swz));
            }
            __builtin_amdgcn_s_setprio(1);
#pragma unroll
            for (int tn = 0; tn < 4; ++tn) {
                v8s bh = *(const v8s*)&w2h[(16 * tn + l15) * 64 + tk * 32 + g * 8];
                v8s bl = *(const v8s*)&w2l[(16 * tn + l15) * 64 + tk * 32 + g * 8];
#pragma unroll
                for (int tm = 0; tm < 4; ++tm) { MFMA3(acc2[tm][tn], ah[tm], al[tm], bh, bl) }
            }
            __builtin_amdgcn_s_setprio(0);
        }

        // ---- H2 prep: hi -> persistent plane [0,8192); lo -> transient [8192,+4K)
        v8s al3[4][2];
#pragma unroll
        for (int tk = 0; tk < 2; ++tk) {
#pragma unroll
            for (int t2 = 0; t2 < 2; ++t2) {
                int tn = 2 * tk + t2;
                int fc = 16 * t2 + l15;
#pragma unroll
                for (int tm = 0; tm < 4; ++tm) {
                    unsigned hp0, lp0, hp1, lp1;
                    cvt_split2(fmaxf(acc2[tm][tn][0], 0.f),
                               fmaxf(acc2[tm][tn][1], 0.f), hp0, lp0);
                    cvt_split2(fmaxf(acc2[tm][tn][2], 0.f),
                               fmaxf(acc2[tm][tn][3], 0.f), hp1, lp1);
#pragma unroll
                    for (int r = 0; r < 4; ++r) {
                        int row = 16 * tm + 4 * g + r;
                        unsigned hv = (r == 0) ? hp0 : (r == 1) ? (hp0 >> 16)
                                    : (r == 2) ? hp1 : (hp1 >> 16);
                        unsigned lv = (r == 0) ? lp0 : (r == 1) ? (lp0 >> 16)
                                    : (r == 2) ? lp1 : (lp1 >> 16);
                        *(u16*)(smem + row * 128 + (((32 * tk + fc) * 2) ^ ((row & 7) << 4))) = (u16)hv;
                        *(u16*)(smem + 8192 + row * 64 + ((fc * 2) ^ ((row & 3) << 4))) = (u16)lv;
                    }
                }
            }
#pragma unroll
            for (int tm = 0; tm < 4; ++tm) {
                int row = 16 * tm + l15;
                al3[tm][tk] = *(const v8s*)(smem + 8192 + row * 64 + ((g * 16) ^ ((row & 3) << 4)));
            }
        }

        // ---- layer 3 + fused epilogue, per output half h
#pragma unroll
        for (int h = 0; h < 2; ++h) {
            v4f acc3[4][4];
#pragma unroll
            for (int tn = 0; tn < 4; ++tn) {
                float bv = b3f[64 * h + 16 * tn + l15];
#pragma unroll
                for (int tm = 0; tm < 4; ++tm) acc3[tm][tn] = (v4f){bv, bv, bv, bv};
            }
            __builtin_amdgcn_s_setprio(1);
#pragma unroll
            for (int tk = 0; tk < 2; ++tk)
#pragma unroll
                for (int tn = 0; tn < 4; ++tn) {
                    int nrow = 16 * (4 * h + tn) + l15;
                    v8s bh = *(const v8s*)&w3h[nrow * 64 + tk * 32 + g * 8];
                    v8s bl = *(const v8s*)&w3l[nrow * 64 + tk * 32 + g * 8];
#pragma unroll
                    for (int tm = 0; tm < 4; ++tm) {
                        int row = 16 * tm + l15;
                        v8s ah = *(const v8s*)(smem + row * 128 +
                                  ((64 * tk + g * 16) ^ ((row & 7) << 4)));
                        MFMA3(acc3[tm][tn], ah, al3[tm][tk], bh, bl)
                    }
                }
            __builtin_amdgcn_s_setprio(0);

            // epilogue: 4 chunks x 16 edges via the 4KB region
            float runmax = -__builtin_inff();
            bool first = true;
#pragma unroll
            for (int c = 0; c < 4; ++c) {
#pragma unroll
                for (int tn = 0; tn < 4; ++tn)
#pragma unroll
                    for (int r = 0; r < 4; ++r) {
                        int rl = 4 * g + r;
                        int col = 16 * tn + l15;
                        int off = 8192 + rl * 256 + ((col * 4) ^ ((rl & 7) << 4));
                        *(float*)(smem + off) = acc3[c][tn][r];
                    }
#pragma unroll
                for (int i = 0; i < 16; ++i) {
                    int e2 = 16 * c + i;
                    int off = 8192 + i * 256 + ((lane * 4) ^ ((i & 7) << 4));
                    float val = *(const float*)(smem + off);
                    runmax = fmaxf(runmax, val);
                    if ((segmask >> e2) & 1ull) {
                        int n = __builtin_amdgcn_readlane(nid, e2);
                        if (n >= 0) {
                            float* op = out + (size_t)n * 128 + h * 64 + lane;
                            if (first || e2 == 63) atomicMax(op, runmax);
                            else *op = runmax;
                        }
                        first = false;
                        runmax = -__builtin_inff();
                    }
                }
            }
        }
#undef STAGE_HALF
    }
}

extern "C" void kernel_launch(void* const* d_in, const int* in_sizes, int n_in,
                              void* d_out, int out_size, void* d_ws, size_t ws_size,
                              hipStream_t stream) {
    const float* x   = (const float*)d_in[0];
    const float* pos = (const float*)d_in[1];
    const float* W1  = (const float*)d_in[2];
    const float* b1  = (const float*)d_in[3];
    const float* g1  = (const float*)d_in[4];
    const float* be1 = (const float*)d_in[5];
    const float* m1  = (const float*)d_in[6];
    const float* v1  = (const float*)d_in[7];
    const float* W2  = (const float*)d_in[8];
    const float* b2  = (const float*)d_in[9];
    const float* g2  = (const float*)d_in[10];
    const float* be2 = (const float*)d_in[11];
    const float* m2  = (const float*)d_in[12];
    const float* v2  = (const float*)d_in[13];
    const float* W3  = (const float*)d_in[14];
    const float* b3  = (const float*)d_in[15];
    const float* g3  = (const float*)d_in[16];
    const float* be3 = (const float*)d_in[17];
    const float* m3  = (const float*)d_in[18];
    const float* v3  = (const float*)d_in[19];
    const int*   ei  = (const int*)d_in[20];

    char* ws = (char*)d_ws;
    u16* w1h = (u16*)(ws + WS_W1H);
    u16* w1l = (u16*)(ws + WS_W1L);
    u16* w2h = (u16*)(ws + WS_W2H);
    u16* w2l = (u16*)(ws + WS_W2L);
    u16* w3h = (u16*)(ws + WS_W3H);
    u16* w3l = (u16*)(ws + WS_W3L);
    float* b1f = (float*)(ws + WS_B1F);
    float* b2f = (float*)(ws + WS_B2F);
    float* b3f = (float*)(ws + WS_B3F);
    int* bsum   = (int*)(ws + WS_BSUM);
    int* cursor = (int*)(ws + WS_CURSOR);
    int2* sorted = (int2*)(ws + WS_SORT);
    float* outf = (float*)d_out;

    hipMemsetAsync(cursor, 0, (size_t)N_NODES * sizeof(int), stream);

    prep0_kernel<<<(N_NODES * 128 / 4 + 255) / 256, 256, 0, stream>>>(
        W1, b1, g1, be1, m1, v1, W2, b2, g2, be2, m2, v2,
        W3, b3, g3, be3, m3, v3, ei, w1h, w1l, w2h, w2l, w3h, w3l,
        b1f, b2f, b3f, cursor, (uint4*)d_out);

    scanA_kernel<<<SCAN_NB, 256, 0, stream>>>(cursor, bsum);
    scanB_kernel<<<1, 256, 0, stream>>>(bsum);
    scatter_kernel<<<(TOT_E + 255) / 256, 256, 0, stream>>>(ei, cursor, bsum, sorted);

    gather_kernel<<<(TOT_E + 127) / 128, 64, 0, stream>>>(
        x, pos, sorted, w1h, w1l, w2h, w2l, w3h, w3l, b1f, b2f, b3f, outf);
}

// Round 23
// 254.802 us; speedup vs baseline: 1.3981x; 1.3981x over previous
//
#include <hip/hip_runtime.h>

#define N_NODES 50000
#define N_EDGES 800000
#define TOT_E   (N_EDGES + N_NODES)
#define EPS     1e-5f
#define SCAN_NB 196                      // ceil(N_NODES/256)

typedef unsigned short u16;
typedef short v8s __attribute__((ext_vector_type(8)));
typedef float v4f __attribute__((ext_vector_type(4)));

// workspace byte offsets
#define WS_W1H    0          // [64 n][32 k] bf16 hi plane   4096 B
#define WS_W1L    4096       // lo plane                     4096 B
#define WS_W2H    8192       // [64 n][64 k]                 8192 B
#define WS_W2L    16384
#define WS_W3H    24576      // [128 n][64 k]               16384 B
#define WS_W3L    40960
#define WS_B1F    57344      // 64 f32
#define WS_B2F    57600
#define WS_B3F    57856      // 128 f32
#define WS_BSUM   58368      // SCAN_NB ints (padded to 1024)
#define WS_CURSOR 59392      // N_NODES ints -> ends at 259392
#define WS_SORT   259392     // TOT_E int2 (8B aligned), 6.8 MB

__device__ __forceinline__ unsigned rne_bf16(float f) {
    unsigned u = __float_as_uint(f);
    return (u + 0x7fffu + ((u >> 16) & 1u)) >> 16;
}

// pairwise fp32 -> (bf16-hi, bf16-lo residual) via v_cvt_pk_bf16_f32 inline asm
// (guide T12/m240: no builtin on gfx950). dst = bf16(s1)<<16 | bf16(s0).
__device__ __forceinline__ void cvt_split2(float v0, float v1,
                                           unsigned &hp, unsigned &lp) {
    unsigned h;
    asm("v_cvt_pk_bf16_f32 %0, %1, %2" : "=v"(h) : "v"(v0), "v"(v1));
    float h0f = __uint_as_float(h << 16);
    float h1f = __uint_as_float(h & 0xffff0000u);
    unsigned l;
    float r0 = v0 - h0f, r1 = v1 - h1f;
    asm("v_cvt_pk_bf16_f32 %0, %1, %2" : "=v"(l) : "v"(r0), "v"(r1));
    hp = h; lp = l;
}

#define MFMA3(acc, ah, al, bh, bl)                                           \
    acc = __builtin_amdgcn_mfma_f32_16x16x32_bf16(ah, bh, acc, 0, 0, 0);     \
    acc = __builtin_amdgcn_mfma_f32_16x16x32_bf16(ah, bl, acc, 0, 0, 0);     \
    acc = __builtin_amdgcn_mfma_f32_16x16x32_bf16(al, bh, acc, 0, 0, 0);

// fused: weight fold + cursor=1 + out=-inf  (one launch)
__global__ void prep0_kernel(
    const float* __restrict__ W1, const float* __restrict__ b1,
    const float* __restrict__ g1, const float* __restrict__ be1,
    const float* __restrict__ m1, const float* __restrict__ v1,
    const float* __restrict__ W2, const float* __restrict__ b2,
    const float* __restrict__ g2, const float* __restrict__ be2,
    const float* __restrict__ m2, const float* __restrict__ v2,
    const float* __restrict__ W3, const float* __restrict__ b3,
    const float* __restrict__ g3, const float* __restrict__ be3,
    const float* __restrict__ m3, const float* __restrict__ v3,
    u16* __restrict__ w1h, u16* __restrict__ w1l,
    u16* __restrict__ w2h, u16* __restrict__ w2l,
    u16* __restrict__ w3h, u16* __restrict__ w3l,
    float* __restrict__ b1f, float* __restrict__ b2f, float* __restrict__ b3f,
    int* __restrict__ cursor, uint4* __restrict__ out4)
{
    int t = blockIdx.x * blockDim.x + threadIdx.x;

    if (t < N_NODES) cursor[t] = 1;                       // self loop count
    if (t < (N_NODES * 128) / 4)
        out4[t] = make_uint4(0xFF800000u, 0xFF800000u, 0xFF800000u, 0xFF800000u);

    if (t < 14592) {
        float val = 0.f;
        u16 *ph = nullptr, *pl = nullptr;
        int idx = 0;
        if (t < 2048) {                       // W1 [n][32k], k>=6 zero
            int n = t >> 5, k = t & 31;
            float s = g1[n] * rsqrtf(v1[n] + EPS);
            val = (k < 6) ? W1[k * 64 + n] * s : 0.f;
            ph = w1h; pl = w1l; idx = t;
        } else if (t < 6144) {                // W2 [n][64k]
            int i = t - 2048; int n = i >> 6, k = i & 63;
            float s = g2[n] * rsqrtf(v2[n] + EPS);
            val = W2[k * 64 + n] * s;
            ph = w2h; pl = w2l; idx = i;
        } else if (t < 14336) {               // W3 [n][64k]
            int i = t - 6144; int n = i >> 6, k = i & 63;
            float s = g3[n] * rsqrtf(v3[n] + EPS);
            val = W3[k * 128 + n] * s;
            ph = w3h; pl = w3l; idx = i;
        } else {                              // biases
            int i = t - 14336;
            if (i < 64) {
                float s = g1[i] * rsqrtf(v1[i] + EPS);
                b1f[i] = (b1[i] - m1[i]) * s + be1[i];
            } else if (i < 128) {
                int j = i - 64;
                float s = g2[j] * rsqrtf(v2[j] + EPS);
                b2f[j] = (b2[j] - m2[j]) * s + be2[j];
            } else {
                int j = i - 128;
                float s = g3[j] * rsqrtf(v3[j] + EPS);
                b3f[j] = (b3[j] - m3[j]) * s + be3[j];
            }
            return;
        }
        unsigned hi = rne_bf16(val);
        unsigned lo = rne_bf16(val - __uint_as_float(hi << 16));
        ph[idx] = (u16)hi;
        pl[idx] = (u16)lo;
    }
}

__global__ void hist_kernel(const int* __restrict__ ei, int* __restrict__ cursor) {
    int e = blockIdx.x * 256 + threadIdx.x;
    if (e < N_EDGES) atomicAdd(&cursor[ei[N_EDGES + e]], 1);
}

// A) per-block exclusive scan + block sums
__global__ void scanA_kernel(int* __restrict__ cursor, int* __restrict__ bsum) {
    __shared__ int sh[256];
    const int tid = threadIdx.x;
    int i = blockIdx.x * 256 + tid;
    int c = (i < N_NODES) ? cursor[i] : 0;
    sh[tid] = c;
    __syncthreads();
    int v = c;
    for (int off = 1; off < 256; off <<= 1) {
        int t = (tid >= off) ? sh[tid - off] : 0;
        __syncthreads();
        v += t;
        sh[tid] = v;
        __syncthreads();
    }
    if (i < N_NODES) cursor[i] = v - c;           // exclusive within block
    if (tid == 255) bsum[blockIdx.x] = v;         // block total
}

// B) exclusive scan of the block sums
__global__ void scanB_kernel(int* __restrict__ bsum) {
    __shared__ int sh[256];
    const int tid = threadIdx.x;
    int c = (tid < SCAN_NB) ? bsum[tid] : 0;
    sh[tid] = c;
    __syncthreads();
    int v = c;
    for (int off = 1; off < 256; off <<= 1) {
        int t = (tid >= off) ? sh[tid - off] : 0;
        __syncthreads();
        v += t;
        sh[tid] = v;
        __syncthreads();
    }
    if (tid < SCAN_NB) bsum[tid] = v - c;
}

// scatter: dst-sorted (src,dst) pairs written directly
__global__ void scatter_kernel(const int* __restrict__ ei, int* __restrict__ cursor,
                               const int* __restrict__ bsum, int2* __restrict__ sorted) {
    int e = blockIdx.x * 256 + threadIdx.x;
    if (e >= TOT_E) return;
    int s, d;
    if (e < N_EDGES) { s = ei[e]; d = ei[N_EDGES + e]; }
    else             { s = d = e - N_EDGES; }
    int p = atomicAdd(&cursor[d], 1);
    sorted[p + bsum[d >> 8]] = make_int2(s, d);
}

// r18 gather (session best, 255.8 us total): (64,2) = the kernel's true
// register appetite (~256/wave incl AGPRs); every occupancy-raising or
// live-range-extending variant spilled (r7,r9,r12,r13,r14,r19,r20,r22).
__global__ __launch_bounds__(64, 2) void gather_kernel(
    const float* __restrict__ x, const float* __restrict__ pos,
    const int2* __restrict__ sorted,
    const u16* __restrict__ w1h, const u16* __restrict__ w1l,
    const u16* __restrict__ w2h, const u16* __restrict__ w2l,
    const u16* __restrict__ w3h, const u16* __restrict__ w3l,
    const float* __restrict__ b1f, const float* __restrict__ b2f,
    const float* __restrict__ b3f, float* __restrict__ out)
{
    __shared__ char smem[12288];

    const int lane = threadIdx.x;
    const int l15 = lane & 15, g = lane >> 4;
    const int e = blockIdx.x * 64 + lane;
    const bool active = e < TOT_E;

    int src = 0, dst = 0;
    if (active) {
        int2 sd = sorted[e];
        src = sd.x; dst = sd.y;
    }
    const int nid = active ? dst : (-1 - lane);   // unique negatives in tail

    // full-exec-mask shuffles only (round-4 lesson)
    const int np1 = __shfl_down(nid, 1);
    const bool seg_last = (lane == 63) || (np1 != nid);
    const unsigned long long segmask = __ballot(seg_last);  // bit63 always set

    float f0 = x[src * 3 + 0];
    float f1 = x[src * 3 + 1];
    float f2v = x[src * 3 + 2];
    float f3 = pos[src * 3 + 0] - pos[dst * 3 + 0];
    float f4 = pos[src * 3 + 1] - pos[dst * 3 + 1];
    float f5 = pos[src * 3 + 2] - pos[dst * 3 + 2];

    unsigned uh0, ul0, uh1, ul1, uh2, ul2;
    cvt_split2(f0, f1, uh0, ul0);
    cvt_split2(f2v, f3, uh1, ul1);
    cvt_split2(f4, f5, uh2, ul2);

    // L1 A-frags via bpermute (edge 16tm+l15's features; g>0 lanes are k>=8 -> 0)
    v8s a1h[4], a1l[4];
#pragma unroll
    for (int tm = 0; tm < 4; ++tm) {
        int bidx = (16 * tm + l15) * 4;
        unsigned p0 = (unsigned)__builtin_amdgcn_ds_bpermute(bidx, (int)uh0);
        unsigned p1 = (unsigned)__builtin_amdgcn_ds_bpermute(bidx, (int)uh1);
        unsigned p2 = (unsigned)__builtin_amdgcn_ds_bpermute(bidx, (int)uh2);
        unsigned q0 = (unsigned)__builtin_amdgcn_ds_bpermute(bidx, (int)ul0);
        unsigned q1 = (unsigned)__builtin_amdgcn_ds_bpermute(bidx, (int)ul1);
        unsigned q2 = (unsigned)__builtin_amdgcn_ds_bpermute(bidx, (int)ul2);
        if (g != 0) { p0 = p1 = p2 = q0 = q1 = q2 = 0u; }
        uint4 th = make_uint4(p0, p1, p2, 0u);
        uint4 tl = make_uint4(q0, q1, q2, 0u);
        a1h[tm] = __builtin_bit_cast(v8s, th);
        a1l[tm] = __builtin_bit_cast(v8s, tl);
    }

    // ---- layer 1
    v4f acc[4][4];
#pragma unroll
    for (int tn = 0; tn < 4; ++tn) {
        float bv = b1f[16 * tn + l15];
#pragma unroll
        for (int tm = 0; tm < 4; ++tm) acc[tm][tn] = (v4f){bv, bv, bv, bv};
    }
#pragma unroll
    for (int tn = 0; tn < 4; ++tn) {
        v8s bh = *(const v8s*)&w1h[(16 * tn + l15) * 32 + g * 8];
        v8s bl = *(const v8s*)&w1l[(16 * tn + l15) * 32 + g * 8];
#pragma unroll
        for (int tm = 0; tm < 4; ++tm) { MFMA3(acc[tm][tn], a1h[tm], a1l[tm], bh, bl) }
    }

    // H1 transient staging into [0,8192): [row][32hi|32lo] u16, 128B rows
#define STAGE_HALF(ACC, tk)                                                      \
    {                                                                            \
        _Pragma("unroll")                                                        \
        for (int t2 = 0; t2 < 2; ++t2) {                                         \
            int tn = 2 * (tk) + t2;                                              \
            int fc = 16 * t2 + l15;                                              \
            _Pragma("unroll")                                                    \
            for (int tm = 0; tm < 4; ++tm) {                                     \
                unsigned hp0, lp0, hp1, lp1;                                     \
                cvt_split2(fmaxf(ACC[tm][tn][0], 0.f),                           \
                           fmaxf(ACC[tm][tn][1], 0.f), hp0, lp0);                \
                cvt_split2(fmaxf(ACC[tm][tn][2], 0.f),                           \
                           fmaxf(ACC[tm][tn][3], 0.f), hp1, lp1);                \
                _Pragma("unroll")                                                \
                for (int r = 0; r < 4; ++r) {                                    \
                    int row = 16 * tm + 4 * g + r;                               \
                    unsigned hv = (r == 0) ? hp0 : (r == 1) ? (hp0 >> 16)        \
                                : (r == 2) ? hp1 : (hp1 >> 16);                  \
                    unsigned lv = (r == 0) ? lp0 : (r == 1) ? (lp0 >> 16)        \
                                : (r == 2) ? lp1 : (lp1 >> 16);                  \
                    int swz = (row & 7) << 4;                                    \
                    *(u16*)(smem + row * 128 + ((fc * 2) ^ swz)) = (u16)hv;      \
                    *(u16*)(smem + row * 128 + ((64 + fc * 2) ^ swz)) = (u16)lv; \
                }                                                                \
            }                                                                    \
        }                                                                        \
    }

    // ---- layer 2: two k-half passes
    v4f acc2[4][4];
#pragma unroll
    for (int tn = 0; tn < 4; ++tn) {
        float bv = b2f[16 * tn + l15];
#pragma unroll
        for (int tm = 0; tm < 4; ++tm) acc2[tm][tn] = (v4f){bv, bv, bv, bv};
    }
#pragma unroll
    for (int tk = 0; tk < 2; ++tk) {
        STAGE_HALF(acc, tk)
        v8s ah[4], al[4];
#pragma unroll
        for (int tm = 0; tm < 4; ++tm) {
            int row = 16 * tm + l15;
            int swz = (row & 7) << 4;
            ah[tm] = *(const v8s*)(smem + row * 128 + ((g * 16) ^ swz));
            al[tm] = *(const v8s*)(smem + row * 128 + ((64 + g * 16) ^ swz));
        }
#pragma unroll
        for (int tn = 0; tn < 4; ++tn) {
            v8s bh = *(const v8s*)&w2h[(16 * tn + l15) * 64 + tk * 32 + g * 8];
            v8s bl = *(const v8s*)&w2l[(16 * tn + l15) * 64 + tk * 32 + g * 8];
#pragma unroll
            for (int tm = 0; tm < 4; ++tm) { MFMA3(acc2[tm][tn], ah[tm], al[tm], bh, bl) }
        }
    }

    // ---- H2 prep: hi -> persistent plane [0,8192); lo -> transient [8192,+4K)
    v8s al3[4][2];
#pragma unroll
    for (int tk = 0; tk < 2; ++tk) {
#pragma unroll
        for (int t2 = 0; t2 < 2; ++t2) {
            int tn = 2 * tk + t2;
            int fc = 16 * t2 + l15;
#pragma unroll
            for (int tm = 0; tm < 4; ++tm) {
                unsigned hp0, lp0, hp1, lp1;
                cvt_split2(fmaxf(acc2[tm][tn][0], 0.f),
                           fmaxf(acc2[tm][tn][1], 0.f), hp0, lp0);
                cvt_split2(fmaxf(acc2[tm][tn][2], 0.f),
                           fmaxf(acc2[tm][tn][3], 0.f), hp1, lp1);
#pragma unroll
                for (int r = 0; r < 4; ++r) {
                    int row = 16 * tm + 4 * g + r;
                    unsigned hv = (r == 0) ? hp0 : (r == 1) ? (hp0 >> 16)
                                : (r == 2) ? hp1 : (hp1 >> 16);
                    unsigned lv = (r == 0) ? lp0 : (r == 1) ? (lp0 >> 16)
                                : (r == 2) ? lp1 : (lp1 >> 16);
                    *(u16*)(smem + row * 128 + (((32 * tk + fc) * 2) ^ ((row & 7) << 4))) = (u16)hv;
                    *(u16*)(smem + 8192 + row * 64 + ((fc * 2) ^ ((row & 3) << 4))) = (u16)lv;
                }
            }
        }
#pragma unroll
        for (int tm = 0; tm < 4; ++tm) {
            int row = 16 * tm + l15;
            al3[tm][tk] = *(const v8s*)(smem + 8192 + row * 64 + ((g * 16) ^ ((row & 3) << 4)));
        }
    }

    // ---- layer 3 + fused epilogue, per output half h
#pragma unroll
    for (int h = 0; h < 2; ++h) {
        v4f acc3[4][4];
#pragma unroll
        for (int tn = 0; tn < 4; ++tn) {
            float bv = b3f[64 * h + 16 * tn + l15];
#pragma unroll
            for (int tm = 0; tm < 4; ++tm) acc3[tm][tn] = (v4f){bv, bv, bv, bv};
        }
#pragma unroll
        for (int tk = 0; tk < 2; ++tk)
#pragma unroll
            for (int tn = 0; tn < 4; ++tn) {
                int nrow = 16 * (4 * h + tn) + l15;
                v8s bh = *(const v8s*)&w3h[nrow * 64 + tk * 32 + g * 8];
                v8s bl = *(const v8s*)&w3l[nrow * 64 + tk * 32 + g * 8];
#pragma unroll
                for (int tm = 0; tm < 4; ++tm) {
                    int row = 16 * tm + l15;
                    v8s ah = *(const v8s*)(smem + row * 128 +
                              ((64 * tk + g * 16) ^ ((row & 7) << 4)));
                    MFMA3(acc3[tm][tn], ah, al3[tm][tk], bh, bl)
                }
            }

        // epilogue: 4 chunks x 16 edges via the 4KB region
        float runmax = -__builtin_inff();
        bool first = true;
#pragma unroll
        for (int c = 0; c < 4; ++c) {
#pragma unroll
            for (int tn = 0; tn < 4; ++tn)
#pragma unroll
                for (int r = 0; r < 4; ++r) {
                    int rl = 4 * g + r;
                    int col = 16 * tn + l15;
                    int off = 8192 + rl * 256 + ((col * 4) ^ ((rl & 7) << 4));
                    *(float*)(smem + off) = acc3[c][tn][r];
                }
#pragma unroll
            for (int i = 0; i < 16; ++i) {
                int e2 = 16 * c + i;
                int off = 8192 + i * 256 + ((lane * 4) ^ ((i & 7) << 4));
                float val = *(const float*)(smem + off);
                runmax = fmaxf(runmax, val);
                if ((segmask >> e2) & 1ull) {
                    int n = __builtin_amdgcn_readlane(nid, e2);
                    if (n >= 0) {
                        float* op = out + (size_t)n * 128 + h * 64 + lane;
                        if (first || e2 == 63) atomicMax(op, runmax);
                        else *op = runmax;
                    }
                    first = false;
                    runmax = -__builtin_inff();
                }
            }
        }
    }
#undef STAGE_HALF
}

extern "C" void kernel_launch(void* const* d_in, const int* in_sizes, int n_in,
                              void* d_out, int out_size, void* d_ws, size_t ws_size,
                              hipStream_t stream) {
    const float* x   = (const float*)d_in[0];
    const float* pos = (const float*)d_in[1];
    const float* W1  = (const float*)d_in[2];
    const float* b1  = (const float*)d_in[3];
    const float* g1  = (const float*)d_in[4];
    const float* be1 = (const float*)d_in[5];
    const float* m1  = (const float*)d_in[6];
    const float* v1  = (const float*)d_in[7];
    const float* W2  = (const float*)d_in[8];
    const float* b2  = (const float*)d_in[9];
    const float* g2  = (const float*)d_in[10];
    const float* be2 = (const float*)d_in[11];
    const float* m2  = (const float*)d_in[12];
    const float* v2  = (const float*)d_in[13];
    const float* W3  = (const float*)d_in[14];
    const float* b3  = (const float*)d_in[15];
    const float* g3  = (const float*)d_in[16];
    const float* be3 = (const float*)d_in[17];
    const float* m3  = (const float*)d_in[18];
    const float* v3  = (const float*)d_in[19];
    const int*   ei  = (const int*)d_in[20];

    char* ws = (char*)d_ws;
    u16* w1h = (u16*)(ws + WS_W1H);
    u16* w1l = (u16*)(ws + WS_W1L);
    u16* w2h = (u16*)(ws + WS_W2H);
    u16* w2l = (u16*)(ws + WS_W2L);
    u16* w3h = (u16*)(ws + WS_W3H);
    u16* w3l = (u16*)(ws + WS_W3L);
    float* b1f = (float*)(ws + WS_B1F);
    float* b2f = (float*)(ws + WS_B2F);
    float* b3f = (float*)(ws + WS_B3F);
    int* bsum   = (int*)(ws + WS_BSUM);
    int* cursor = (int*)(ws + WS_CURSOR);
    int2* sorted = (int2*)(ws + WS_SORT);
    float* outf = (float*)d_out;

    prep0_kernel<<<(N_NODES * 128 / 4 + 255) / 256, 256, 0, stream>>>(
        W1, b1, g1, be1, m1, v1, W2, b2, g2, be2, m2, v2,
        W3, b3, g3, be3, m3, v3, w1h, w1l, w2h, w2l, w3h, w3l,
        b1f, b2f, b3f, cursor, (uint4*)d_out);

    hist_kernel<<<(N_EDGES + 255) / 256, 256, 0, stream>>>(ei, cursor);
    scanA_kernel<<<SCAN_NB, 256, 0, stream>>>(cursor, bsum);
    scanB_kernel<<<1, 256, 0, stream>>>(bsum);
    scatter_kernel<<<(TOT_E + 255) / 256, 256, 0, stream>>>(ei, cursor, bsum, sorted);

    gather_kernel<<<(TOT_E + 63) / 64, 64, 0, stream>>>(
        x, pos, sorted, w1h, w1l, w2h, w2l, w3h, w3l, b1f, b2f, b3f, outf);
}